// Round 1
// baseline (2597.755 us; speedup 1.0000x reference)
//
#include <hip/hip_runtime.h>
#include <math.h>

// ---------- helpers ----------
__device__ __forceinline__ unsigned enc_f(float f) {
    int i = __float_as_int(f);
    return (i >= 0) ? (unsigned(i) | 0x80000000u) : ~unsigned(i);
}
__device__ __forceinline__ float dec_f(unsigned u) {
    int i = (u & 0x80000000u) ? int(u & 0x7FFFFFFFu) : int(~u);
    return __int_as_float(i);
}

// ---------- GEMM: Y1 = X@W1, Y2 = X@W2 ; X [n,IN], W [IN,C] row-major ----------
// block = 2*C threads, 16 rows per block. xs broadcast from LDS, W coalesced.
template <int IN, int C>
__global__ __launch_bounds__(256) void gemm_two(
    const float* __restrict__ X, const float* __restrict__ W1,
    const float* __restrict__ W2, float* __restrict__ Y1,
    float* __restrict__ Y2, int n) {
    __shared__ float xs[16][IN];
    const int tid = threadIdx.x;
    const int row0 = blockIdx.x * 16;
    for (int i = tid; i < 16 * IN; i += 2 * C) {
        int r = i / IN, k = i - r * IN;
        int gr = row0 + r;
        xs[r][k] = (gr < n) ? X[(size_t)gr * IN + k] : 0.f;
    }
    __syncthreads();
    const float* W = (tid < C) ? W1 : W2;
    float* Y = (tid < C) ? Y1 : Y2;
    const int col = (tid < C) ? tid : (tid - C);
    float acc[16];
#pragma unroll
    for (int r = 0; r < 16; ++r) acc[r] = 0.f;
    for (int k = 0; k < IN; ++k) {
        float w = W[k * C + col];
#pragma unroll
        for (int r = 0; r < 16; ++r) acc[r] = fmaf(xs[r][k], w, acc[r]);
    }
#pragma unroll
    for (int r = 0; r < 16; ++r) {
        int gr = row0 + r;
        if (gr < n) Y[(size_t)gr * C + col] = acc[r];
    }
}

// ---------- edge logits + segment max ----------
// 16 lanes per (edge,head) slot; head dim fixed 64 (16 float4 lanes).
template <int H>
__global__ __launch_bounds__(256) void edge_logits_k(
    const float* __restrict__ xl, const float* __restrict__ xr,
    const int* __restrict__ srcs, const int* __restrict__ dsts,
    const float* __restrict__ att, float* __restrict__ logits,
    unsigned* __restrict__ m_enc, int e0, int etot) {
    const int HC = H * 64;
    const int lane = threadIdx.x & 63;
    const int group = lane >> 4, l16 = lane & 15;
    const long long wave = ((long long)blockIdx.x * blockDim.x + threadIdx.x) >> 6;
    const long long nw = ((long long)gridDim.x * blockDim.x) >> 6;
    const long long tot = (long long)etot * H;
    for (long long s0 = wave * 4; s0 < tot; s0 += nw * 4) {
        long long slot = s0 + group;
        float partial = 0.f;
        int d = 0;
        bool valid = slot < tot;
        if (valid) {
            int e = (int)((H == 1) ? slot : (slot >> 1));
            int h = (H == 1) ? 0 : (int)(slot & 1);
            int sidx = (e < e0) ? srcs[e] : (e - e0);
            d = (e < e0) ? dsts[e] : (e - e0);
            float4 a = reinterpret_cast<const float4*>(xl + (size_t)sidx * HC + h * 64)[l16];
            float4 b = reinterpret_cast<const float4*>(xr + (size_t)d * HC + h * 64)[l16];
            float4 at = reinterpret_cast<const float4*>(att + h * 64)[l16];
            float v;
            v = a.x + b.x; partial = fmaf(at.x, (v > 0.f ? v : 0.2f * v), partial);
            v = a.y + b.y; partial = fmaf(at.y, (v > 0.f ? v : 0.2f * v), partial);
            v = a.z + b.z; partial = fmaf(at.z, (v > 0.f ? v : 0.2f * v), partial);
            v = a.w + b.w; partial = fmaf(at.w, (v > 0.f ? v : 0.2f * v), partial);
        }
#pragma unroll
        for (int msk = 8; msk >= 1; msk >>= 1) partial += __shfl_xor(partial, msk, 64);
        if (valid && l16 == 0) {
            logits[slot] = partial;
            int h = (H == 1) ? 0 : (int)(slot & 1);
            atomicMax(&m_enc[(size_t)d * H + h], enc_f(partial));
        }
    }
}

// ---------- exp + segment sum (in-place logits -> ex) ----------
template <int H>
__global__ __launch_bounds__(256) void edge_exp_k(
    const int* __restrict__ dsts, float* __restrict__ exbuf,
    const unsigned* __restrict__ m_enc, float* __restrict__ ssum,
    int e0, int etot) {
    long long tot = (long long)etot * H;
    for (long long slot = (long long)blockIdx.x * blockDim.x + threadIdx.x; slot < tot;
         slot += (long long)gridDim.x * blockDim.x) {
        int e = (int)((H == 1) ? slot : (slot >> 1));
        int h = (H == 1) ? 0 : (int)(slot & 1);
        int d = (e < e0) ? dsts[e] : (e - e0);
        float m = dec_f(m_enc[(size_t)d * H + h]);
        float v = expf(exbuf[slot] - m);
        exbuf[slot] = v;
        unsafeAtomicAdd(&ssum[(size_t)d * H + h], v);
    }
}

// ---------- weighted scatter-add ----------
template <int H>
__global__ __launch_bounds__(256) void edge_scatter_k(
    const float* __restrict__ xl, const int* __restrict__ srcs,
    const int* __restrict__ dsts, const float* __restrict__ exbuf,
    const float* __restrict__ ssum, float* __restrict__ accum,
    int e0, int etot) {
    const int HC = H * 64;
    const int lane = threadIdx.x & 63;
    const int group = lane >> 4, l16 = lane & 15;
    const long long wave = ((long long)blockIdx.x * blockDim.x + threadIdx.x) >> 6;
    const long long nw = ((long long)gridDim.x * blockDim.x) >> 6;
    const long long tot = (long long)etot * H;
    for (long long s0 = wave * 4; s0 < tot; s0 += nw * 4) {
        long long slot = s0 + group;
        if (slot >= tot) continue;
        int e = (int)((H == 1) ? slot : (slot >> 1));
        int h = (H == 1) ? 0 : (int)(slot & 1);
        int sidx = (e < e0) ? srcs[e] : (e - e0);
        int d = (e < e0) ? dsts[e] : (e - e0);
        float alpha = exbuf[slot] / (ssum[(size_t)d * H + h] + 1e-16f);
        float4 a = reinterpret_cast<const float4*>(xl + (size_t)sidx * HC + h * 64)[l16];
        float* dp = accum + (size_t)d * HC + h * 64 + l16 * 4;
        unsafeAtomicAdd(dp + 0, alpha * a.x);
        unsafeAtomicAdd(dp + 1, alpha * a.y);
        unsafeAtomicAdd(dp + 2, alpha * a.z);
        unsafeAtomicAdd(dp + 3, alpha * a.w);
    }
}

// ---------- bias + relu ----------
__global__ __launch_bounds__(256) void finalize_k(
    const float* __restrict__ accum, const float* __restrict__ bias,
    float* __restrict__ out, int n, int ctmask, int ct) {
    long long tot = (long long)n * ct;
    for (long long i = (long long)blockIdx.x * blockDim.x + threadIdx.x; i < tot;
         i += (long long)gridDim.x * blockDim.x) {
        int c = (int)(i & ctmask);
        float v = accum[i] + bias[c];
        out[i] = v > 0.f ? v : 0.f;
    }
}

extern "C" void kernel_launch(void* const* d_in, const int* in_sizes, int n_in,
                              void* d_out, int out_size, void* d_ws, size_t ws_size,
                              hipStream_t stream) {
    const float* x    = (const float*)d_in[0];
    const int*   ei   = (const int*)d_in[1];
    const float* Wl1  = (const float*)d_in[2];
    const float* Wr1  = (const float*)d_in[3];
    const float* att1 = (const float*)d_in[4];
    const float* b1   = (const float*)d_in[5];
    const float* Wl2  = (const float*)d_in[6];
    const float* Wr2  = (const float*)d_in[7];
    const float* att2 = (const float*)d_in[8];
    const float* b2   = (const float*)d_in[9];

    const int n    = in_sizes[0] / 128;   // 50000
    const int e0   = in_sizes[1] / 2;     // 800000
    const int etot = e0 + n;              // + self loops
    const int* srcs = ei;
    const int* dsts = ei + e0;

    float* ws = (float*)d_ws;
    size_t offA = 0;                         // xl  : n*128
    size_t offB = offA + (size_t)n * 128;    // xr  : n*128
    size_t offC = offB + (size_t)n * 128;    // accum / h1 : n*128
    size_t offD = offC + (size_t)n * 128;    // ex  : etot*2
    size_t offM = offD + (size_t)etot * 2;   // m_enc : n*2 (u32)
    size_t offS = offM + (size_t)n * 2;      // ssum  : n*2
    float*    xl   = ws + offA;
    float*    xr   = ws + offB;
    float*    acc  = ws + offC;
    float*    exb  = ws + offD;
    unsigned* menc = (unsigned*)(ws + offM);
    float*    ssum = ws + offS;

    const int eblocks = 4096;
    dim3 gb((n + 15) / 16);

    // ================= layer 1 (H=2, C=64) =================
    hipMemsetAsync(menc, 0, (size_t)n * 2 * sizeof(unsigned), stream);  // enc(x)>0 for all reals
    hipMemsetAsync(ssum, 0, (size_t)n * 2 * sizeof(float), stream);
    hipMemsetAsync(acc,  0, (size_t)n * 128 * sizeof(float), stream);
    gemm_two<128, 128><<<gb, 256, 0, stream>>>(x, Wl1, Wr1, xl, xr, n);
    edge_logits_k<2><<<eblocks, 256, 0, stream>>>(xl, xr, srcs, dsts, att1, exb, menc, e0, etot);
    edge_exp_k<2><<<eblocks, 256, 0, stream>>>(dsts, exb, menc, ssum, e0, etot);
    edge_scatter_k<2><<<eblocks, 256, 0, stream>>>(xl, srcs, dsts, exb, ssum, acc, e0, etot);
    finalize_k<<<2048, 256, 0, stream>>>(acc, b1, acc, n, 127, 128);  // in-place -> h1

    // ================= layer 2 (H=1, C=64) =================
    gemm_two<128, 64><<<gb, 128, 0, stream>>>(acc, Wl2, Wr2, xl, xr, n);
    // acc (h1) is consumed by the GEMM above; stream-ordered memset then reuse as accum2
    hipMemsetAsync(menc, 0, (size_t)n * sizeof(unsigned), stream);
    hipMemsetAsync(ssum, 0, (size_t)n * sizeof(float), stream);
    hipMemsetAsync(acc,  0, (size_t)n * 64 * sizeof(float), stream);
    edge_logits_k<1><<<eblocks, 256, 0, stream>>>(xl, xr, srcs, dsts, att2, exb, menc, e0, etot);
    edge_exp_k<1><<<eblocks, 256, 0, stream>>>(dsts, exb, menc, ssum, e0, etot);
    edge_scatter_k<1><<<eblocks, 256, 0, stream>>>(xl, srcs, dsts, exb, ssum, acc, e0, etot);
    finalize_k<<<2048, 256, 0, stream>>>(acc, b2, (float*)d_out, n, 63, 64);
}

// Round 2
// 412.940 us; speedup vs baseline: 6.2909x; 6.2909x over previous
//
#include <hip/hip_runtime.h>
#include <math.h>

// ---------- GEMM: Y1 = X@W1, Y2 = X@W2 ; X [n,IN], W [IN,C] row-major ----------
template <int IN, int C>
__global__ __launch_bounds__(256) void gemm_two(
    const float* __restrict__ X, const float* __restrict__ W1,
    const float* __restrict__ W2, float* __restrict__ Y1,
    float* __restrict__ Y2, int n) {
    __shared__ float xs[16][IN];
    const int tid = threadIdx.x;
    const int row0 = blockIdx.x * 16;
    for (int i = tid; i < 16 * IN; i += 2 * C) {
        int r = i / IN, k = i - r * IN;
        int gr = row0 + r;
        xs[r][k] = (gr < n) ? X[(size_t)gr * IN + k] : 0.f;
    }
    __syncthreads();
    const float* W = (tid < C) ? W1 : W2;
    float* Y = (tid < C) ? Y1 : Y2;
    const int col = (tid < C) ? tid : (tid - C);
    float acc[16];
#pragma unroll
    for (int r = 0; r < 16; ++r) acc[r] = 0.f;
    for (int k = 0; k < IN; ++k) {
        float w = W[k * C + col];
#pragma unroll
        for (int r = 0; r < 16; ++r) acc[r] = fmaf(xs[r][k], w, acc[r]);
    }
#pragma unroll
    for (int r = 0; r < 16; ++r) {
        int gr = row0 + r;
        if (gr < n) Y[(size_t)gr * C + col] = acc[r];
    }
}

// ---------- CSR build ----------
__global__ __launch_bounds__(256) void count_k(const int* __restrict__ dsts,
                                               int* __restrict__ cnt, int e0) {
    for (int i = blockIdx.x * blockDim.x + threadIdx.x; i < e0;
         i += gridDim.x * blockDim.x)
        atomicAdd(&cnt[dsts[i]], 1);
}

// single-block exclusive scan of (cnt[i] + 1)  [+1 = self loop]
__global__ __launch_bounds__(256) void scan_k(const int* __restrict__ cnt,
                                              int* __restrict__ row_ptr, int n) {
    __shared__ int sums[256];
    const int t = threadIdx.x;
    const int chunk = (n + 255) / 256;
    const int lo = min(t * chunk, n), hi = min(lo + chunk, n);
    int s = 0;
    for (int i = lo; i < hi; ++i) s += cnt[i] + 1;
    sums[t] = s;
    __syncthreads();
    if (t == 0) {
        int run = 0;
        for (int i = 0; i < 256; ++i) { int v = sums[i]; sums[i] = run; run += v; }
    }
    __syncthreads();
    int run = sums[t];
    for (int i = lo; i < hi; ++i) { row_ptr[i] = run; run += cnt[i] + 1; }
    if (t == 255) row_ptr[n] = run;
}

__global__ __launch_bounds__(256) void fill_k(
    const int* __restrict__ srcs, const int* __restrict__ dsts,
    const int* __restrict__ row_ptr, int* __restrict__ cursor,
    int* __restrict__ csr_src, int e0, int etot) {
    for (int i = blockIdx.x * blockDim.x + threadIdx.x; i < etot;
         i += gridDim.x * blockDim.x) {
        int s, d;
        if (i < e0) { s = srcs[i]; d = dsts[i]; } else { s = d = i - e0; }
        int pos = atomicAdd(&cursor[d], 1);
        csr_src[row_ptr[d] + pos] = s;
    }
}

// ---------- fused per-dst online-softmax aggregation ----------
// one wave per (dst, head); 4 groups x 16 lanes; C=64 (16 x float4)
template <int H>
__global__ __launch_bounds__(256) void gat_dst_k(
    const float* __restrict__ xl, const float* __restrict__ xr,
    const int* __restrict__ row_ptr, const int* __restrict__ csr_src,
    const float* __restrict__ att, const float* __restrict__ bias,
    float* __restrict__ out, int n) {
    const int HC = H * 64;
    const int lane = threadIdx.x & 63;
    const int g = lane >> 4, l16 = lane & 15;
    const int w = (blockIdx.x * blockDim.x + threadIdx.x) >> 6;
    const int nslots = n * H;
    if (w >= nslots) return;
    const int d = (H == 1) ? w : (w >> 1);
    const int h = (H == 1) ? 0 : (w & 1);

    const float4 xrv = reinterpret_cast<const float4*>(xr + (size_t)d * HC + h * 64)[l16];
    const float4 atv = reinterpret_cast<const float4*>(att + h * 64)[l16];
    const int rp0 = row_ptr[d], rp1 = row_ptr[d + 1];

    float m = -3.0e38f, s = 0.f;
    float4 acc = {0.f, 0.f, 0.f, 0.f};

    for (int i = rp0 + g; i < rp1; i += 4) {
        const int src = csr_src[i];
        const float4 a = reinterpret_cast<const float4*>(xl + (size_t)src * HC + h * 64)[l16];
        float v, p = 0.f;
        v = a.x + xrv.x; p = fmaf(atv.x, (v > 0.f ? v : 0.2f * v), p);
        v = a.y + xrv.y; p = fmaf(atv.y, (v > 0.f ? v : 0.2f * v), p);
        v = a.z + xrv.z; p = fmaf(atv.z, (v > 0.f ? v : 0.2f * v), p);
        v = a.w + xrv.w; p = fmaf(atv.w, (v > 0.f ? v : 0.2f * v), p);
#pragma unroll
        for (int msk = 8; msk >= 1; msk >>= 1) p += __shfl_xor(p, msk, 64);
        const float mn = fmaxf(m, p);
        const float sc = __expf(m - mn);
        const float wg = __expf(p - mn);
        s = s * sc + wg;
        acc.x = fmaf(acc.x, sc, wg * a.x);
        acc.y = fmaf(acc.y, sc, wg * a.y);
        acc.z = fmaf(acc.z, sc, wg * a.z);
        acc.w = fmaf(acc.w, sc, wg * a.w);
        m = mn;
    }
    // combine the 4 groups' partial softmax states
#pragma unroll
    for (int off = 16; off <= 32; off <<= 1) {
        const float mo = __shfl_xor(m, off, 64);
        const float so = __shfl_xor(s, off, 64);
        float4 ao;
        ao.x = __shfl_xor(acc.x, off, 64);
        ao.y = __shfl_xor(acc.y, off, 64);
        ao.z = __shfl_xor(acc.z, off, 64);
        ao.w = __shfl_xor(acc.w, off, 64);
        const float mn = fmaxf(m, mo);
        const float sc = __expf(m - mn), sco = __expf(mo - mn);
        s = s * sc + so * sco;
        acc.x = acc.x * sc + ao.x * sco;
        acc.y = acc.y * sc + ao.y * sco;
        acc.z = acc.z * sc + ao.z * sco;
        acc.w = acc.w * sc + ao.w * sco;
        m = mn;
    }
    if (g == 0) {
        const float inv = 1.f / (s + 1e-16f);
        const float4 bv = reinterpret_cast<const float4*>(bias + h * 64)[l16];
        float4 o;
        o.x = fmaxf(fmaf(acc.x, inv, bv.x), 0.f);
        o.y = fmaxf(fmaf(acc.y, inv, bv.y), 0.f);
        o.z = fmaxf(fmaf(acc.z, inv, bv.z), 0.f);
        o.w = fmaxf(fmaf(acc.w, inv, bv.w), 0.f);
        reinterpret_cast<float4*>(out + (size_t)d * HC + h * 64)[l16] = o;
    }
}

extern "C" void kernel_launch(void* const* d_in, const int* in_sizes, int n_in,
                              void* d_out, int out_size, void* d_ws, size_t ws_size,
                              hipStream_t stream) {
    const float* x    = (const float*)d_in[0];
    const int*   ei   = (const int*)d_in[1];
    const float* Wl1  = (const float*)d_in[2];
    const float* Wr1  = (const float*)d_in[3];
    const float* att1 = (const float*)d_in[4];
    const float* b1   = (const float*)d_in[5];
    const float* Wl2  = (const float*)d_in[6];
    const float* Wr2  = (const float*)d_in[7];
    const float* att2 = (const float*)d_in[8];
    const float* b2   = (const float*)d_in[9];

    const int n    = in_sizes[0] / 128;   // 50000
    const int e0   = in_sizes[1] / 2;     // 800000
    const int etot = e0 + n;
    const int* srcs = ei;
    const int* dsts = ei + e0;

    float* ws = (float*)d_ws;
    float* xl = ws;                          // n*128
    float* xr = xl + (size_t)n * 128;        // n*128
    float* h1 = xr + (size_t)n * 128;        // n*128
    int* row_ptr = (int*)(h1 + (size_t)n * 128);  // n+1
    int* cnt     = row_ptr + (n + 1);             // n (reused as cursor)
    int* csr_src = cnt + n;                       // etot

    // ---- CSR build (graph identical for both layers) ----
    hipMemsetAsync(cnt, 0, (size_t)n * sizeof(int), stream);
    count_k<<<2048, 256, 0, stream>>>(dsts, cnt, e0);
    scan_k<<<1, 256, 0, stream>>>(cnt, row_ptr, n);
    hipMemsetAsync(cnt, 0, (size_t)n * sizeof(int), stream);  // -> cursor
    fill_k<<<2048, 256, 0, stream>>>(srcs, dsts, row_ptr, cnt, csr_src, e0, etot);

    dim3 gb((n + 15) / 16);

    // ---- layer 1 (H=2, C=64) ----
    gemm_two<128, 128><<<gb, 256, 0, stream>>>(x, Wl1, Wr1, xl, xr, n);
    gat_dst_k<2><<<(n * 2 + 3) / 4, 256, 0, stream>>>(xl, xr, row_ptr, csr_src,
                                                      att1, b1, h1, n);
    // ---- layer 2 (H=1, C=64) ----
    gemm_two<128, 64><<<gb, 128, 0, stream>>>(h1, Wl2, Wr2, xl, xr, n);
    gat_dst_k<1><<<(n + 3) / 4, 256, 0, stream>>>(xl, xr, row_ptr, csr_src,
                                                  att2, b2, (float*)d_out, n);
}

// Round 3
// 338.412 us; speedup vs baseline: 7.6763x; 1.2202x over previous
//
#include <hip/hip_runtime.h>
#include <math.h>

// ---------- GEMM: Y1 = X@W1, Y2 = X@W2 ; X [n,IN], W [IN,C] row-major ----------
template <int IN, int C>
__global__ __launch_bounds__(256) void gemm_two(
    const float* __restrict__ X, const float* __restrict__ W1,
    const float* __restrict__ W2, float* __restrict__ Y1,
    float* __restrict__ Y2, int n) {
    __shared__ float xs[16][IN];
    const int tid = threadIdx.x;
    const int row0 = blockIdx.x * 16;
    for (int i = tid; i < 16 * IN; i += 2 * C) {
        int r = i / IN, k = i - r * IN;
        int gr = row0 + r;
        xs[r][k] = (gr < n) ? X[(size_t)gr * IN + k] : 0.f;
    }
    __syncthreads();
    const float* W = (tid < C) ? W1 : W2;
    float* Y = (tid < C) ? Y1 : Y2;
    const int col = (tid < C) ? tid : (tid - C);
    float acc[16];
#pragma unroll
    for (int r = 0; r < 16; ++r) acc[r] = 0.f;
    for (int k = 0; k < IN; ++k) {
        float w = W[k * C + col];
#pragma unroll
        for (int r = 0; r < 16; ++r) acc[r] = fmaf(xs[r][k], w, acc[r]);
    }
#pragma unroll
    for (int r = 0; r < 16; ++r) {
        int gr = row0 + r;
        if (gr < n) Y[(size_t)gr * C + col] = acc[r];
    }
}

// ---------- CSR build ----------
__global__ __launch_bounds__(256) void count_k(const int* __restrict__ dsts,
                                               int* __restrict__ cnt, int e0) {
    for (int i = blockIdx.x * blockDim.x + threadIdx.x; i < e0;
         i += gridDim.x * blockDim.x)
        atomicAdd(&cnt[dsts[i]], 1);
}

// per-block sums of (cnt[i]+1), 256 elements per block
__global__ __launch_bounds__(256) void bsum_k(const int* __restrict__ cnt,
                                              int* __restrict__ bsum, int n) {
    __shared__ int red[256];
    const int t = threadIdx.x;
    const int i = blockIdx.x * 256 + t;
    red[t] = (i < n) ? cnt[i] + 1 : 0;
    __syncthreads();
#pragma unroll
    for (int s = 128; s > 0; s >>= 1) {
        if (t < s) red[t] += red[t + s];
        __syncthreads();
    }
    if (t == 0) bsum[blockIdx.x] = red[0];
}

// block b: offset = sum(bsum[0..b-1]); Hillis-Steele scan of its 256-chunk.
// Requires nblocks <= 256 (n <= 65536).
__global__ __launch_bounds__(256) void scan2_k(const int* __restrict__ cnt,
                                               const int* __restrict__ bsum,
                                               int* __restrict__ row_ptr, int n) {
    __shared__ int red[256];
    const int b = blockIdx.x, t = threadIdx.x;
    red[t] = (t < b) ? bsum[t] : 0;
    __syncthreads();
#pragma unroll
    for (int s = 128; s > 0; s >>= 1) {
        if (t < s) red[t] += red[t + s];
        __syncthreads();
    }
    const int offset = red[0];
    __syncthreads();
    const int i = b * 256 + t;
    const int x = (i < n) ? cnt[i] + 1 : 0;
    red[t] = x;
    __syncthreads();
#pragma unroll
    for (int s = 1; s < 256; s <<= 1) {
        const int add = (t >= s) ? red[t - s] : 0;
        __syncthreads();
        red[t] += add;
        __syncthreads();
    }
    if (i < n) row_ptr[i] = offset + red[t] - x;        // exclusive
    if (i == n - 1) row_ptr[n] = offset + red[t];       // total
}

__global__ __launch_bounds__(256) void fill_k(
    const int* __restrict__ srcs, const int* __restrict__ dsts,
    const int* __restrict__ row_ptr, int* __restrict__ cursor,
    int* __restrict__ csr_src, int e0, int etot) {
    for (int i = blockIdx.x * blockDim.x + threadIdx.x; i < etot;
         i += gridDim.x * blockDim.x) {
        int s, d;
        if (i < e0) { s = srcs[i]; d = dsts[i]; } else { s = d = i - e0; }
        int pos = atomicAdd(&cursor[d], 1);
        csr_src[row_ptr[d] + pos] = s;
    }
}

// ---------- fused per-dst online-softmax aggregation ----------
// one wave per (dst, head); 4 groups x 16 lanes; C=64 (16 x float4)
template <int H>
__global__ __launch_bounds__(256) void gat_dst_k(
    const float* __restrict__ xl, const float* __restrict__ xr,
    const int* __restrict__ row_ptr, const int* __restrict__ csr_src,
    const float* __restrict__ att, const float* __restrict__ bias,
    float* __restrict__ out, int n) {
    const int HC = H * 64;
    const int lane = threadIdx.x & 63;
    const int g = lane >> 4, l16 = lane & 15;
    const int w = (blockIdx.x * blockDim.x + threadIdx.x) >> 6;
    const int nslots = n * H;
    if (w >= nslots) return;
    const int d = (H == 1) ? w : (w >> 1);
    const int h = (H == 1) ? 0 : (w & 1);

    const float4 xrv = reinterpret_cast<const float4*>(xr + (size_t)d * HC + h * 64)[l16];
    const float4 atv = reinterpret_cast<const float4*>(att + h * 64)[l16];
    const int rp0 = row_ptr[d], rp1 = row_ptr[d + 1];

    float m = -3.0e38f, s = 0.f;
    float4 acc = {0.f, 0.f, 0.f, 0.f};

    for (int i = rp0 + g; i < rp1; i += 4) {
        const int src = csr_src[i];
        const float4 a = reinterpret_cast<const float4*>(xl + (size_t)src * HC + h * 64)[l16];
        float v, p = 0.f;
        v = a.x + xrv.x; p = fmaf(atv.x, (v > 0.f ? v : 0.2f * v), p);
        v = a.y + xrv.y; p = fmaf(atv.y, (v > 0.f ? v : 0.2f * v), p);
        v = a.z + xrv.z; p = fmaf(atv.z, (v > 0.f ? v : 0.2f * v), p);
        v = a.w + xrv.w; p = fmaf(atv.w, (v > 0.f ? v : 0.2f * v), p);
#pragma unroll
        for (int msk = 8; msk >= 1; msk >>= 1) p += __shfl_xor(p, msk, 64);
        const float mn = fmaxf(m, p);
        const float sc = __expf(m - mn);
        const float wg = __expf(p - mn);
        s = s * sc + wg;
        acc.x = fmaf(acc.x, sc, wg * a.x);
        acc.y = fmaf(acc.y, sc, wg * a.y);
        acc.z = fmaf(acc.z, sc, wg * a.z);
        acc.w = fmaf(acc.w, sc, wg * a.w);
        m = mn;
    }
    // combine the 4 groups' partial softmax states
#pragma unroll
    for (int off = 16; off <= 32; off <<= 1) {
        const float mo = __shfl_xor(m, off, 64);
        const float so = __shfl_xor(s, off, 64);
        float4 ao;
        ao.x = __shfl_xor(acc.x, off, 64);
        ao.y = __shfl_xor(acc.y, off, 64);
        ao.z = __shfl_xor(acc.z, off, 64);
        ao.w = __shfl_xor(acc.w, off, 64);
        const float mn = fmaxf(m, mo);
        const float sc = __expf(m - mn), sco = __expf(mo - mn);
        s = s * sc + so * sco;
        acc.x = acc.x * sc + ao.x * sco;
        acc.y = acc.y * sc + ao.y * sco;
        acc.z = acc.z * sc + ao.z * sco;
        acc.w = acc.w * sc + ao.w * sco;
        m = mn;
    }
    if (g == 0) {
        const float inv = 1.f / (s + 1e-16f);
        const float4 bv = reinterpret_cast<const float4*>(bias + h * 64)[l16];
        float4 o;
        o.x = fmaxf(fmaf(acc.x, inv, bv.x), 0.f);
        o.y = fmaxf(fmaf(acc.y, inv, bv.y), 0.f);
        o.z = fmaxf(fmaf(acc.z, inv, bv.z), 0.f);
        o.w = fmaxf(fmaf(acc.w, inv, bv.w), 0.f);
        reinterpret_cast<float4*>(out + (size_t)d * HC + h * 64)[l16] = o;
    }
}

extern "C" void kernel_launch(void* const* d_in, const int* in_sizes, int n_in,
                              void* d_out, int out_size, void* d_ws, size_t ws_size,
                              hipStream_t stream) {
    const float* x    = (const float*)d_in[0];
    const int*   ei   = (const int*)d_in[1];
    const float* Wl1  = (const float*)d_in[2];
    const float* Wr1  = (const float*)d_in[3];
    const float* att1 = (const float*)d_in[4];
    const float* b1   = (const float*)d_in[5];
    const float* Wl2  = (const float*)d_in[6];
    const float* Wr2  = (const float*)d_in[7];
    const float* att2 = (const float*)d_in[8];
    const float* b2   = (const float*)d_in[9];

    const int n    = in_sizes[0] / 128;   // 50000
    const int e0   = in_sizes[1] / 2;     // 800000
    const int etot = e0 + n;
    const int* srcs = ei;
    const int* dsts = ei + e0;

    float* ws = (float*)d_ws;
    float* xl = ws;                          // n*128
    float* xr = xl + (size_t)n * 128;        // n*128
    float* h1 = xr + (size_t)n * 128;        // n*128
    int* row_ptr = (int*)(h1 + (size_t)n * 128);  // n+1
    int* cnt     = row_ptr + (n + 1);             // n (reused as cursor)
    int* bsum    = cnt + n;                       // nblocks (<=256)
    int* csr_src = bsum + 256;                    // etot

    const int nb = (n + 255) / 256;  // 196 <= 256

    // ---- CSR build (graph identical for both layers) ----
    hipMemsetAsync(cnt, 0, (size_t)n * sizeof(int), stream);
    count_k<<<2048, 256, 0, stream>>>(dsts, cnt, e0);
    bsum_k<<<nb, 256, 0, stream>>>(cnt, bsum, n);
    scan2_k<<<nb, 256, 0, stream>>>(cnt, bsum, row_ptr, n);
    hipMemsetAsync(cnt, 0, (size_t)n * sizeof(int), stream);  // -> cursor
    fill_k<<<2048, 256, 0, stream>>>(srcs, dsts, row_ptr, cnt, csr_src, e0, etot);

    dim3 gb((n + 15) / 16);

    // ---- layer 1 (H=2, C=64) ----
    gemm_two<128, 128><<<gb, 256, 0, stream>>>(x, Wl1, Wr1, xl, xr, n);
    gat_dst_k<2><<<(n * 2 + 3) / 4, 256, 0, stream>>>(xl, xr, row_ptr, csr_src,
                                                      att1, b1, h1, n);
    // ---- layer 2 (H=1, C=64) ----
    gemm_two<128, 64><<<gb, 128, 0, stream>>>(h1, Wl2, Wr2, xl, xr, n);
    gat_dst_k<1><<<(n + 3) / 4, 256, 0, stream>>>(xl, xr, row_ptr, csr_src,
                                                  att2, b2, (float*)d_out, n);
}